// Round 10
// baseline (423.558 us; speedup 1.0000x reference)
//
#include <hip/hip_runtime.h>

#define HID 32
#define DLAT 97
#define NPG 100
#define TOPK 30
#define MAXZ 1000
#define BKT_NODES 128   // nodes per bucket (bucket = dst >> 7)
#define BKT_SHIFT 7
#define MAXBKT 1024     // >= ceil(N/128); N=100000 -> 782
#define CAP 3072        // max edges per bucket held in LDS (exp 2046, sigma 45)
#define CHUNK 8192      // edges per binning block

// ---------------- binning: partition edges by dst bucket ----------------

__global__ __launch_bounds__(256) void binA_kernel(const int* __restrict__ dst,
                                                   int* __restrict__ bucket_cnt, int E) {
    __shared__ int hist[MAXBKT];
    for (int t = threadIdx.x; t < MAXBKT; t += 256) hist[t] = 0;
    __syncthreads();
    int base = blockIdx.x * CHUNK;
    int lim = min(E, base + CHUNK);
    for (int e = base + threadIdx.x; e < lim; e += 256)
        atomicAdd(&hist[dst[e] >> BKT_SHIFT], 1);
    __syncthreads();
    for (int t = threadIdx.x; t < MAXBKT; t += 256) {
        int v = hist[t];
        if (v) atomicAdd(&bucket_cnt[t], v);
    }
}

// single block: exclusive scan of bucket_cnt[1024] -> bucket_start, cursor
__global__ __launch_bounds__(MAXBKT) void bscan_kernel(const int* __restrict__ bucket_cnt,
                                                       int* __restrict__ bucket_start,
                                                       int* __restrict__ cursor) {
    __shared__ int sh[MAXBKT];
    int t = threadIdx.x;
    int v = bucket_cnt[t];
    sh[t] = v;
    __syncthreads();
    for (int off = 1; off < MAXBKT; off <<= 1) {
        int tv = (t >= off) ? sh[t - off] : 0;
        __syncthreads();
        sh[t] += tv;
        __syncthreads();
    }
    int excl = sh[t] - v;
    bucket_start[t] = excl;
    cursor[t] = excl;
    if (t == MAXBKT - 1) bucket_start[MAXBKT] = sh[t];  // = E
}

// LDS dst-cache + hist -> reserve ranges -> scatter (dst read ONCE from global)
__global__ __launch_bounds__(256) void binB_kernel(const int* __restrict__ src,
                                                   const int* __restrict__ dst,
                                                   const float* __restrict__ ew,
                                                   int* __restrict__ cursor,
                                                   int2* __restrict__ bedge, int E) {
    __shared__ int hist[MAXBKT];
    __shared__ int lcur[MAXBKT];
    __shared__ int dcache[CHUNK];
    for (int t = threadIdx.x; t < MAXBKT; t += 256) hist[t] = 0;
    __syncthreads();
    int base = blockIdx.x * CHUNK;
    int M = min(E - base, CHUNK);
    for (int i = threadIdx.x; i < M; i += 256) {
        int d = dst[base + i];
        dcache[i] = d;
        atomicAdd(&hist[d >> BKT_SHIFT], 1);
    }
    __syncthreads();
    for (int t = threadIdx.x; t < MAXBKT; t += 256) {
        int v = hist[t];
        lcur[t] = v ? atomicAdd(&cursor[t], v) : 0;
    }
    __syncthreads();
    for (int i = threadIdx.x; i < M; i += 256) {
        int d = dcache[i];
        int slot = atomicAdd(&lcur[d >> BKT_SHIFT], 1);
        bedge[slot] = make_int2(src[base + i] | ((d & (BKT_NODES - 1)) << 20),
                                __float_as_int(ew[base + i]));
    }
}

// per-bucket counting sort, LDS-resident; emits csr + row_start + dinv + ni={z,dinv}
__global__ __launch_bounds__(256) void sortlocal_kernel(
    const int2* __restrict__ bedge, const int* __restrict__ bucket_start,
    const int* __restrict__ z, int2* __restrict__ csr, int* __restrict__ row_start,
    float* __restrict__ dinv, int2* __restrict__ ni, int N, int E) {
    __shared__ int2 LDSe[CAP];          // 24 KB
    __shared__ int cnt[BKT_NODES];
    __shared__ int sh[BKT_NODES];
    __shared__ int lcur[BKT_NODES];
    __shared__ float facc[BKT_NODES];
    int b = blockIdx.x, t = threadIdx.x;
    int beg = bucket_start[b], end = bucket_start[b + 1], M = end - beg;
    if (t < BKT_NODES) { cnt[t] = 0; facc[t] = 0.f; }
    __syncthreads();
    int n = b * BKT_NODES + t;
    if (M <= CAP) {
        for (int i = t; i < M; i += 256) {
            int2 e = bedge[beg + i];
            LDSe[i] = e;
            atomicAdd(&cnt[(e.x >> 20) & (BKT_NODES - 1)], 1);
        }
        __syncthreads();
        int v = 0;
        if (t < BKT_NODES) { v = cnt[t]; sh[t] = v; }
        __syncthreads();
        for (int off = 1; off < BKT_NODES; off <<= 1) {
            int tv = (t >= off && t < BKT_NODES) ? sh[t - off] : 0;
            __syncthreads();
            if (t < BKT_NODES) sh[t] += tv;
            __syncthreads();
        }
        int excl = 0;
        if (t < BKT_NODES) {
            excl = sh[t] - v;
            lcur[t] = excl;
            if (n < N) row_start[n] = beg + excl;
        }
        if (b == 0 && t == 0) row_start[N] = E;
        __syncthreads();
        for (int i = t; i < M; i += 256) {
            int2 e = LDSe[i];
            int slot = atomicAdd(&lcur[(e.x >> 20) & (BKT_NODES - 1)], 1);
            csr[beg + slot] = make_int2(e.x & 0xFFFFF, e.y);
        }
        __syncthreads();  // drains this block's global writes before re-read
        if (t < BKT_NODES && n < N) {
            float s = 1.f;
            int s0 = beg + excl;
            for (int i = 0; i < v; ++i) s += __int_as_float(csr[s0 + i].y);
            float di = 1.f / sqrtf(s);
            dinv[n] = di;
            ni[n] = make_int2(z[n], __float_as_int(di));
        }
    } else {
        // fallback (not expected): two-pass from global
        for (int i = beg + t; i < end; i += 256) {
            int2 e = bedge[i];
            int loc = (e.x >> 20) & (BKT_NODES - 1);
            atomicAdd(&cnt[loc], 1);
            atomicAdd(&facc[loc], __int_as_float(e.y));
        }
        __syncthreads();
        int v = 0;
        if (t < BKT_NODES) { v = cnt[t]; sh[t] = v; }
        __syncthreads();
        for (int off = 1; off < BKT_NODES; off <<= 1) {
            int tv = (t >= off && t < BKT_NODES) ? sh[t - off] : 0;
            __syncthreads();
            if (t < BKT_NODES) sh[t] += tv;
            __syncthreads();
        }
        if (t < BKT_NODES) {
            int excl = sh[t] - v;
            lcur[t] = excl;
            if (n < N) {
                row_start[n] = beg + excl;
                float di = 1.f / sqrtf(1.f + facc[t]);
                dinv[n] = di;
                ni[n] = make_int2(z[n], __float_as_int(di));
            }
        }
        if (b == 0 && t == 0) row_start[N] = E;
        __syncthreads();
        for (int i = beg + t; i < end; i += 256) {
            int2 e = bedge[i];
            int slot = atomicAdd(&lcur[(e.x >> 20) & (BKT_NODES - 1)], 1);
            csr[beg + slot] = make_int2(e.x & 0xFFFFF, e.y);
        }
    }
}

// T[zi][f] = dot(z_emb[zi], W1[:,f])  — 1000x32, L2-resident lookup table
__global__ void ztab_kernel(const float* __restrict__ z_emb, const float* __restrict__ W,
                            float* __restrict__ T) {
    int tid = blockIdx.x * blockDim.x + threadIdx.x;
    if (tid >= MAXZ * HID) return;
    int zi = tid >> 5, f = tid & 31;
    const float* row = z_emb + (size_t)zi * HID;
    float s = 0.f;
#pragma unroll
    for (int k = 0; k < HID; ++k) s += row[k] * W[k * HID + f];
    T[tid] = s;
}

// ---------------- layer-1 aggregation via z-table (all L2-resident) ----------------
// out[n][f] = tanh(di_n*(sum_e (ew_e*di_src)*T[z_src][f] + di_n*T[z_n][f]) + b1[f])
// epilogue: xw_next[n][f'] = di_n * sum_k out[k]*W2[k][f']   (prescaled for layer 2)
__global__ __launch_bounds__(256) void agg1st_kernel(
    const int* __restrict__ row_start, const int2* __restrict__ csr,
    const int2* __restrict__ ni, const float* __restrict__ T,
    const float* __restrict__ b, const float* __restrict__ Wn,
    float* __restrict__ concat, float* __restrict__ xw_next, int N) {
    int tid = blockIdx.x * blockDim.x + threadIdx.x;
    int n = tid >> 5;
    if (n >= N) return;
    int f = threadIdx.x & 31;
    int beg = row_start[n], end = row_start[n + 1];
    float s0 = 0.f, s1 = 0.f;
    for (int i = beg; i < end; i += 8) {
        int2 e[8];
#pragma unroll
        for (int j = 0; j < 8; ++j) e[j] = csr[min(i + j, end - 1)];
        int2 nio[8];
#pragma unroll
        for (int j = 0; j < 8; ++j) nio[j] = ni[e[j].x];
        float x[8];
#pragma unroll
        for (int j = 0; j < 8; ++j) x[j] = T[nio[j].x * HID + f];
#pragma unroll
        for (int j = 0; j < 8; ++j) {
            float w = (i + j < end)
                          ? __int_as_float(e[j].y) * __int_as_float(nio[j].y) : 0.f;
            if (j & 1) s1 += w * x[j];
            else       s0 += w * x[j];
        }
    }
    float s = s0 + s1;
    int2 me = ni[n];
    float di = __int_as_float(me.y);
    float outv = tanhf(di * (s + di * T[me.x * HID + f]) + b[f]);
    concat[(size_t)n * DLAT + f] = outv;  // col 0
    float p = 0.f;
#pragma unroll
    for (int k = 0; k < HID; ++k) {
        float ok = __shfl(outv, k, 32);
        p += ok * Wn[k * HID + f];
    }
    xw_next[(size_t)n * HID + f] = p * di;
}

// ---------------- layers 2/3: fused aggregation + next-layer xw GEMM ----------------
template <int MODE>
__global__ __launch_bounds__(256) void agg32f_kernel(
    const int* __restrict__ row_start, const int2* __restrict__ csr,
    const float* __restrict__ xw, const float* __restrict__ b,
    const float* __restrict__ dinv, const float* __restrict__ Wn,
    float* __restrict__ concat, int col_off, float* __restrict__ xw_next, int N) {
    int tid = blockIdx.x * blockDim.x + threadIdx.x;
    int n = tid >> 5;
    if (n >= N) return;
    int f = threadIdx.x & 31;
    int beg = row_start[n], end = row_start[n + 1];
    float s0 = 0.f, s1 = 0.f;
    for (int i = beg; i < end; i += 8) {
        float w[8];
        int idx[8];
#pragma unroll
        for (int j = 0; j < 8; ++j) {
            int ii = min(i + j, end - 1);   // clamp: duplicate last edge, weight 0
            int2 v = csr[ii];
            idx[j] = v.x;
            w[j] = (i + j < end) ? __int_as_float(v.y) : 0.f;
        }
        float x[8];
#pragma unroll
        for (int j = 0; j < 8; ++j) x[j] = xw[(size_t)idx[j] * HID + f];
#pragma unroll
        for (int j = 0; j < 8; ++j) {
            if (j & 1) s1 += w[j] * x[j];
            else       s0 += w[j] * x[j];
        }
    }
    float s = s0 + s1;
    float di = dinv[n];
    float outv = tanhf(di * (s + xw[(size_t)n * HID + f]) + b[f]);
    concat[(size_t)n * DLAT + col_off + f] = outv;

    if (MODE == 0) {
        float p = 0.f;
#pragma unroll
        for (int k = 0; k < HID; ++k) {
            float ok = __shfl(outv, k, 32);
            p += ok * Wn[k * HID + f];
        }
        xw_next[(size_t)n * HID + f] = p * di;
    } else {
        float p = outv * Wn[f];
        p += __shfl_xor(p, 16);
        p += __shfl_xor(p, 8);
        p += __shfl_xor(p, 4);
        p += __shfl_xor(p, 2);
        p += __shfl_xor(p, 1);
        if (f == 0) xw_next[n] = p * di;
    }
}

// ---- fused: layer-4 agg + tanh + stable top-30 + CNN/MLP head (one block/graph) ----
__global__ __launch_bounds__(128) void topk_head_kernel(
    const int* __restrict__ row_start, const int2* __restrict__ csr,
    const float* __restrict__ xw4, const float* __restrict__ b4,
    const float* __restrict__ dinv, const float* __restrict__ concat,
    const float* __restrict__ Wc1, const float* __restrict__ bc1,
    const float* __restrict__ Wc2, const float* __restrict__ bc2,
    const float* __restrict__ Wl1, const float* __restrict__ bl1,
    const float* __restrict__ Wl2, const float* __restrict__ bl2,
    float* __restrict__ out) {
    int g = blockIdx.x;
    int tid = threadIdx.x;  // 128 threads
    __shared__ float v[NPG];
    __shared__ int tidx[TOPK];
    __shared__ float tval[TOPK];
    __shared__ float top[TOPK * DLAT];
    __shared__ float y1[16 * TOPK];
    __shared__ float y2[16 * 15];
    __shared__ float y3[352];
    __shared__ float r[128];

    if (tid < NPG) {
        int n = g * NPG + tid;
        int beg = row_start[n], end = row_start[n + 1];
        float s = 0.f;
        for (int i = beg; i < end; ++i) {
            int2 e = csr[i];
            s += __int_as_float(e.y) * xw4[e.x];
        }
        v[tid] = tanhf(dinv[n] * (s + xw4[n]) + b4[0]);
    }
    __syncthreads();
    // stable rank select (matches jnp.argsort(-v): lower index wins ties)
    if (tid < NPG) {
        float vi = v[tid];
        int cnt = 0;
#pragma unroll 4
        for (int j = 0; j < NPG; ++j) {
            float vj = v[j];
            cnt += (vj > vi) || (vj == vi && j < tid);
        }
        if (cnt < TOPK) {
            tidx[cnt] = g * NPG + tid;
            tval[cnt] = vi;
        }
    }
    __syncthreads();

    for (int idx = tid; idx < TOPK * DLAT; idx += 128) {
        int k = idx / DLAT, d = idx - k * DLAT;
        top[idx] = (d == 96) ? tval[k] : concat[(size_t)tidx[k] * DLAT + d];
    }
    __syncthreads();

    for (int idx = tid; idx < 16 * TOPK; idx += 128) {
        int c = idx / TOPK, k = idx % TOPK;
        float s = bc1[c];
        const float* w = Wc1 + c * DLAT;
        const float* t = top + k * DLAT;
#pragma unroll 4
        for (int d = 0; d < DLAT; ++d) s += t[d] * w[d];
        y1[c * TOPK + k] = fmaxf(s, 0.f);
    }
    __syncthreads();

    for (int idx = tid; idx < 16 * 15; idx += 128) {
        int c = idx / 15, j = idx % 15;
        y2[idx] = fmaxf(y1[c * TOPK + 2 * j], y1[c * TOPK + 2 * j + 1]);
    }
    __syncthreads();

    for (int idx = tid; idx < 352; idx += 128) {
        int o = idx / 11, t = idx % 11;
        float s = bc2[o];
#pragma unroll
        for (int i = 0; i < 16; ++i) {
#pragma unroll
            for (int k = 0; k < 5; ++k)
                s += Wc2[(o * 16 + i) * 5 + k] * y2[i * 15 + t + k];
        }
        y3[idx] = fmaxf(s, 0.f);
    }
    __syncthreads();

    {
        float s = bl1[tid];
        for (int d = 0; d < 352; ++d) s += y3[d] * Wl1[d * 128 + tid];
        r[tid] = fmaxf(s, 0.f) * Wl2[tid];
    }
    __syncthreads();
    if (tid < 64) r[tid] += r[tid + 64];
    __syncthreads();
    if (tid == 0) {
        float s = 0.f;
        for (int j = 0; j < 64; ++j) s += r[j];
        out[g] = s + bl2[0];
    }
}

// ---------------- launch ----------------

extern "C" void kernel_launch(void* const* d_in, const int* in_sizes, int n_in,
                              void* d_out, int out_size, void* d_ws, size_t ws_size,
                              hipStream_t stream) {
    const int* z = (const int*)d_in[0];
    const int* ei = (const int*)d_in[1];
    const float* ew = (const float*)d_in[3];
    const float* z_emb = (const float*)d_in[4];
    const float* Wg[4] = {(const float*)d_in[5], (const float*)d_in[7],
                          (const float*)d_in[9], (const float*)d_in[11]};
    const float* bg[4] = {(const float*)d_in[6], (const float*)d_in[8],
                          (const float*)d_in[10], (const float*)d_in[12]};
    const float* Wc1 = (const float*)d_in[13];
    const float* bc1 = (const float*)d_in[14];
    const float* Wc2 = (const float*)d_in[15];
    const float* bc2 = (const float*)d_in[16];
    const float* Wl1 = (const float*)d_in[17];
    const float* bl1 = (const float*)d_in[18];
    const float* Wl2 = (const float*)d_in[19];
    const float* bl2 = (const float*)d_in[20];
    float* out = (float*)d_out;

    const int N = in_sizes[0];
    const int E = in_sizes[1] / 2;
    const int G = out_size;  // 1000 graphs
    const int* src = ei;
    const int* dst = ei + E;

    auto cdiv = [](long long a, long long b) { return (int)((a + b - 1) / b); };
    const int NB = cdiv(E, CHUNK);
    const int NBKT = cdiv(N, BKT_NODES);

    // workspace layout (8B-aligned arrays first)
    char* ws = (char*)d_ws;
    int2* bedge = (int2*)ws;                  ws += sizeof(int2) * (size_t)E;
    int2* csr = (int2*)ws;                    ws += sizeof(int2) * (size_t)E;
    int2* ni = (int2*)ws;                     ws += sizeof(int2) * (size_t)N;
    int* bucket_cnt = (int*)ws;               ws += sizeof(int) * MAXBKT;
    int* bucket_start = (int*)ws;             ws += sizeof(int) * (MAXBKT + 1);
    int* cursor = (int*)ws;                   ws += sizeof(int) * MAXBKT;
    int* row_start = (int*)ws;                ws += sizeof(int) * (N + 1);
    float* dinv = (float*)ws;                 ws += sizeof(float) * N;
    float* T = (float*)ws;                    ws += sizeof(float) * MAXZ * HID;
    float* xw_a = (float*)ws;                 ws += sizeof(float) * (size_t)N * HID;
    float* concat = (float*)ws;               ws += sizeof(float) * (size_t)N * DLAT;
    // aliases: xw_b over bedge (dead after sortlocal); xw4 over ni (dead after agg1st)
    float* xw_b = (float*)bedge;
    float* xw4 = (float*)ni;

    const int B = 256;

    // bucket partition (atomic range reservation) + LDS-resident per-bucket sort
    hipMemsetAsync(bucket_cnt, 0, sizeof(int) * MAXBKT, stream);
    binA_kernel<<<NB, B, 0, stream>>>(dst, bucket_cnt, E);
    bscan_kernel<<<1, MAXBKT, 0, stream>>>(bucket_cnt, bucket_start, cursor);
    binB_kernel<<<NB, B, 0, stream>>>(src, dst, ew, cursor, bedge, E);
    sortlocal_kernel<<<NBKT, B, 0, stream>>>(bedge, bucket_start, z, csr, row_start,
                                             dinv, ni, N, E);

    // z-table (z_emb @ W1), then layer-1 agg via L2-resident tables
    ztab_kernel<<<cdiv(MAXZ * HID, B), B, 0, stream>>>(z_emb, Wg[0], T);
    const int AGGB = cdiv((long long)N * 32, B);
    agg1st_kernel<<<AGGB, B, 0, stream>>>(row_start, csr, ni, T, bg[0], Wg[1],
                                          concat, xw_b, N);
    agg32f_kernel<0><<<AGGB, B, 0, stream>>>(row_start, csr, xw_b, bg[1], dinv, Wg[2],
                                             concat, 32, xw_a, N);
    agg32f_kernel<1><<<AGGB, B, 0, stream>>>(row_start, csr, xw_a, bg[2], dinv, Wg[3],
                                             concat, 64, xw4, N);

    // fused layer-4 agg + tanh + top-30 + head
    topk_head_kernel<<<G, 128, 0, stream>>>(row_start, csr, xw4, bg[3], dinv, concat,
                                            Wc1, bc1, Wc2, bc2, Wl1, bl1, Wl2, bl2, out);
}